// Round 13
// baseline (220.844 us; speedup 1.0000x reference)
//
#include <hip/hip_runtime.h>
#include <math.h>

#define NTOK 198
#define CCH  192

typedef float vf2 __attribute__((ext_vector_type(2)));
typedef float vf4 __attribute__((ext_vector_type(4)));

__device__ __forceinline__ float qgelu(float v) {
    return v / (1.0f + __expf(-1.702f * v));  // x * sigmoid(1.702 x)
}

__device__ __forceinline__ float dot8(const float4& a, const float4& wa,
                                      const float4& b, const float4& wb) {
    return a.x*wa.x + a.y*wa.y + a.z*wa.z + a.w*wa.w
         + b.x*wb.x + b.y*wb.y + b.z*wb.z + b.w*wb.w;
}

// Fully fused: down-proj + qgelu -> conv3x3 + qgelu -> up-proj.
// TWO blocks per batch element (row-split, halo recomputed), 256 thr, grid 2048.
// R13: fit under the 64-VGPR cap of (256,4) -> 8 waves/SIMD (occupancy step at
// vgpr<=64 per m69), grid exactly resident in one fill (8 blocks/CU).
// Slimmed: Phase A 2-row x 2-float4 sub-steps (16 buf regs); Phase C 2 ch/thread
// (w_r 16 regs, float2 stores). R10 lesson: (256,4) with a 124-reg body spills
// catastrophically -- the body must actually fit.
__global__ __launch_bounds__(256, 4) void convpass_fused(
    const float* __restrict__ x,       // [B,198,192]
    const float* __restrict__ w_down,  // [8,192]
    const float* __restrict__ b_down,  // [8]
    const float* __restrict__ conv_w,  // [8,8,3,3]
    const float* __restrict__ conv_b,  // [8]
    const float* __restrict__ w_up,    // [192,8]
    const float* __restrict__ b_up,    // [192]
    float* __restrict__ out)           // [B,198,192]
{
    const int half = blockIdx.x;       // 0: cls+dist+rows 0..6 ; 1: rows 7..13
    const int b    = blockIdx.y;
    const int tid  = threadIdx.x;

    // half 0: outputs n in [0,100), needs d tokens [0,114)
    // half 1: outputs n in [100,198), needs d tokens [86,198)
    const int d_start   = half ? 86  : 0;
    const int d_count   = half ? 112 : 114;
    const int out_start = half ? 100 : 0;
    const int out_count = half ? 98  : 100;

    __shared__ float s_w[8 * CCH];    // 6144 B  w_down
    __shared__ float s_d[114 * 8];    // 3648 B  down-proj out (stride 8: b128 rows)
    __shared__ float s_d2[100 * 8];   // 3200 B  conv out
    __shared__ float s_cw[576];       // 2304 B  conv weights [kk][o][i]

    // ---- stage weights ----
    for (int t = tid; t < 8 * CCH; t += 256) s_w[t] = w_down[t];
    for (int t = tid; t < 576; t += 256) {
        const int kk = t >> 6, rem = t & 63, o = rem >> 3, i = rem & 7;
        s_cw[t] = conv_w[(o * 8 + i) * 9 + kk];   // [kk][o][i] <- [o][i][kk]
    }
    __syncthreads();

    // ========== Phase A: d = qgelu(x @ w_down^T + b_down) -> s_d ==========
    // wave = 8 token-slots x 8 c-chunk lanes, TWO rows per lane (w-fragment reuse),
    // 2-float4 sub-steps to keep live buffers at 16 regs.
    {
        const int lane  = tid & 63;
        const int wv    = tid >> 6;       // wave 0..3
        const int t_sub = lane >> 3;      // token-slot 0..7
        const int k     = lane & 7;       // c-chunk (24 floats)
        const float bd  = b_down[k];
        const float* xb = x + (size_t)b * NTOK * CCH;

        #pragma unroll 1
        for (int p = 0; p < 2; ++p) {
            const int iA = p * 64 + wv * 16 + t_sub;
            const int iB = iA + 8;
            const bool vA = (iA < d_count), vB = (iB < d_count);
            const int nA = d_start + (vA ? iA : 0);   // safe addr for masked lanes
            const int nB = d_start + (vB ? iB : 0);
            const float* pA = xb + (size_t)nA * CCH + k * 24;
            const float* pB = xb + (size_t)nB * CCH + k * 24;

            float accA[8] = {0,0,0,0,0,0,0,0};
            float accB[8] = {0,0,0,0,0,0,0,0};
            #pragma unroll
            for (int h3 = 0; h3 < 3; ++h3) {          // 8-float sub-steps
                const float4 xa0 = *(const float4*)(pA + h3 * 8);
                const float4 xa1 = *(const float4*)(pA + h3 * 8 + 4);
                const float4 xv0 = *(const float4*)(pB + h3 * 8);
                const float4 xv1 = *(const float4*)(pB + h3 * 8 + 4);
                #pragma unroll
                for (int dm = 0; dm < 8; ++dm) {
                    // 8 distinct addrs/wave (k), 96B stride -> 2-way banks: free
                    const float4 w0 = *(const float4*)&s_w[dm * CCH + k * 24 + h3 * 8];
                    const float4 w1 = *(const float4*)&s_w[dm * CCH + k * 24 + h3 * 8 + 4];
                    accA[dm] += dot8(xa0, w0, xa1, w1);
                    accB[dm] += dot8(xv0, w0, xv1, w1);
                }
            }
            float oA = 0.f, oB = 0.f;
            #pragma unroll
            for (int dm = 0; dm < 8; ++dm) {
                float a = accA[dm];
                a += __shfl_xor(a, 1); a += __shfl_xor(a, 2); a += __shfl_xor(a, 4);
                float c = accB[dm];
                c += __shfl_xor(c, 1); c += __shfl_xor(c, 2); c += __shfl_xor(c, 4);
                oA = (dm == k) ? a : oA;
                oB = (dm == k) ? c : oB;
            }
            if (vA) s_d[iA * 8 + k] = qgelu(oA + bd);
            if (vB) s_d[iB * 8 + k] = qgelu(oB + bd);
        }
    }
    __syncthreads();

    // ========== Phase B: conv3x3 + qgelu -> s_d2 (b128 reads) ==========
    for (int j = tid; j < out_count * 8; j += 256) {
        const int nr = j >> 3, o = j & 7;
        const int n = out_start + nr;
        if (n == 1) {
            s_d2[j] = 0.0f;            // dist token zeroed; qgelu(0)=0
        } else if (n == 0) {           // cls: center tap only (half 0: s_d idx0 = tok 0)
            const float4 d0 = *(const float4*)&s_d[0];
            const float4 d1 = *(const float4*)&s_d[4];
            const float4 w0 = *(const float4*)&s_cw[4 * 64 + o * 8];
            const float4 w1 = *(const float4*)&s_cw[4 * 64 + o * 8 + 4];
            s_d2[j] = qgelu(conv_b[o] + dot8(d0, w0, d1, w1));
        } else {
            const int pos = n - 2, h = pos / 14, w = pos % 14;
            float acc = conv_b[o];
            #pragma unroll
            for (int dh = -1; dh <= 1; ++dh) {
                const int hh = h + dh;
                if (hh < 0 || hh > 13) continue;
                #pragma unroll
                for (int dw = -1; dw <= 1; ++dw) {
                    const int ww = w + dw;
                    if (ww < 0 || ww > 13) continue;
                    const int tok = 2 + hh * 14 + ww;
                    const int kk  = (dh + 1) * 3 + (dw + 1);
                    const int ti  = tok - d_start;
                    const float4 d0 = *(const float4*)&s_d[ti * 8];
                    const float4 d1 = *(const float4*)&s_d[ti * 8 + 4];
                    const float4 w0 = *(const float4*)&s_cw[kk * 64 + o * 8];
                    const float4 w1 = *(const float4*)&s_cw[kk * 64 + o * 8 + 4];
                    acc += dot8(d0, w0, d1, w1);
                }
            }
            s_d2[j] = qgelu(acc);
        }
    }
    __syncthreads();

    // ========== Phase C: out = d2 @ w_up^T + b_up  (2 channels/thread) ==========
    const int c2 = tid % 96;   // channel pair: channels 2*c2, 2*c2+1
    const int tl = tid / 96;   // 0,1 active; tl==2 (64 threads) idle
    if (tl < 2) {
        const int ch = c2 * 2;
        const float4 wa0 = *(const float4*)(w_up + ch * 8);
        const float4 wa1 = *(const float4*)(w_up + ch * 8 + 4);
        const float4 wb0 = *(const float4*)(w_up + ch * 8 + 8);
        const float4 wb1 = *(const float4*)(w_up + ch * 8 + 12);
        const float bu0 = b_up[ch], bu1 = b_up[ch + 1];
        float* outb = out + ((size_t)b * NTOK + out_start) * CCH;
        #pragma unroll 1
        for (int nr = tl; nr < out_count; nr += 2) {
            const float4 da = *(const float4*)&s_d2[nr * 8];      // broadcast
            const float4 dv = *(const float4*)&s_d2[nr * 8 + 4];
            const vf2 r = {bu0 + dot8(da, wa0, dv, wa1),
                           bu1 + dot8(da, wb0, dv, wb1)};
            __builtin_nontemporal_store(r, (vf2*)(outb + (size_t)nr * CCH + ch));
        }
    }
}

extern "C" void kernel_launch(void* const* d_in, const int* in_sizes, int n_in,
                              void* d_out, int out_size, void* d_ws, size_t ws_size,
                              hipStream_t stream) {
    const float* x      = (const float*)d_in[0];
    const float* w_down = (const float*)d_in[1];
    const float* b_down = (const float*)d_in[2];
    const float* conv_w = (const float*)d_in[3];
    const float* conv_b = (const float*)d_in[4];
    const float* w_up   = (const float*)d_in[5];
    const float* b_up   = (const float*)d_in[6];
    float* out = (float*)d_out;

    const int B = in_sizes[0] / (NTOK * CCH);   // 1024
    convpass_fused<<<dim3(2, B), dim3(256), 0, stream>>>(
        x, w_down, b_down, conv_w, conv_b, w_up, b_up, out);
}

// Round 14
// 184.737 us; speedup vs baseline: 1.1954x; 1.1954x over previous
//
#include <hip/hip_runtime.h>
#include <math.h>

#define NTOK 198
#define CCH  192

typedef float vf2 __attribute__((ext_vector_type(2)));
typedef float vf4 __attribute__((ext_vector_type(4)));

__device__ __forceinline__ float qgelu(float v) {
    return v / (1.0f + __expf(-1.702f * v));  // x * sigmoid(1.702 x)
}

__device__ __forceinline__ float dot8(const float4& a, const float4& wa,
                                      const float4& b, const float4& wb) {
    return a.x*wa.x + a.y*wa.y + a.z*wa.z + a.w*wa.w
         + b.x*wb.x + b.y*wb.y + b.z*wb.z + b.w*wb.w;
}

// Fully fused: down-proj + qgelu -> conv3x3 + qgelu -> up-proj.
// TWO blocks per batch element (row-split, halo recomputed), 256 thr, grid 2048.
// Reg ladder learned R7..R13: cap = 256/arg2; body needs (85,128] unconstrained;
// cap 64 => ~600MB scratch. R14: arg2=3 (cap ~85) + tame Phase B unroll (the
// likely 128-reg driver: 9 taps x 4 hoisted b128 loads). Goal: 5-6 waves/SIMD.
__global__ __launch_bounds__(256, 3) void convpass_fused(
    const float* __restrict__ x,       // [B,198,192]
    const float* __restrict__ w_down,  // [8,192]
    const float* __restrict__ b_down,  // [8]
    const float* __restrict__ conv_w,  // [8,8,3,3]
    const float* __restrict__ conv_b,  // [8]
    const float* __restrict__ w_up,    // [192,8]
    const float* __restrict__ b_up,    // [192]
    float* __restrict__ out)           // [B,198,192]
{
    const int half = blockIdx.x;       // 0: cls+dist+rows 0..6 ; 1: rows 7..13
    const int b    = blockIdx.y;
    const int tid  = threadIdx.x;

    // half 0: outputs n in [0,100), needs d tokens [0,114)
    // half 1: outputs n in [100,198), needs d tokens [86,198)
    const int d_start   = half ? 86  : 0;
    const int d_count   = half ? 112 : 114;
    const int out_start = half ? 100 : 0;
    const int out_count = half ? 98  : 100;

    __shared__ float s_w[8 * CCH];    // 6144 B  w_down
    __shared__ float s_d[114 * 8];    // 3648 B  down-proj out (stride 8: b128 rows)
    __shared__ float s_d2[100 * 8];   // 3200 B  conv out
    __shared__ float s_cw[576];       // 2304 B  conv weights [kk][o][i]

    // ---- stage weights ----
    for (int t = tid; t < 8 * CCH; t += 256) s_w[t] = w_down[t];
    for (int t = tid; t < 576; t += 256) {
        const int kk = t >> 6, rem = t & 63, o = rem >> 3, i = rem & 7;
        s_cw[t] = conv_w[(o * 8 + i) * 9 + kk];   // [kk][o][i] <- [o][i][kk]
    }
    __syncthreads();

    // ========== Phase A: d = qgelu(x @ w_down^T + b_down) -> s_d ==========
    // wave = 8 token-slots x 8 c-chunk lanes, TWO rows per lane (w-fragment reuse),
    // 8-float sub-steps (16 live buffer regs).
    {
        const int lane  = tid & 63;
        const int wv    = tid >> 6;       // wave 0..3
        const int t_sub = lane >> 3;      // token-slot 0..7
        const int k     = lane & 7;       // c-chunk (24 floats)
        const float bd  = b_down[k];
        const float* xb = x + (size_t)b * NTOK * CCH;

        #pragma unroll 1
        for (int p = 0; p < 2; ++p) {
            const int iA = p * 64 + wv * 16 + t_sub;
            const int iB = iA + 8;
            const bool vA = (iA < d_count), vB = (iB < d_count);
            const int nA = d_start + (vA ? iA : 0);   // safe addr for masked lanes
            const int nB = d_start + (vB ? iB : 0);
            const float* pA = xb + (size_t)nA * CCH + k * 24;
            const float* pB = xb + (size_t)nB * CCH + k * 24;

            float accA[8] = {0,0,0,0,0,0,0,0};
            float accB[8] = {0,0,0,0,0,0,0,0};
            #pragma unroll
            for (int h3 = 0; h3 < 3; ++h3) {          // 8-float sub-steps
                const float4 xa0 = *(const float4*)(pA + h3 * 8);
                const float4 xa1 = *(const float4*)(pA + h3 * 8 + 4);
                const float4 xv0 = *(const float4*)(pB + h3 * 8);
                const float4 xv1 = *(const float4*)(pB + h3 * 8 + 4);
                #pragma unroll
                for (int dm = 0; dm < 8; ++dm) {
                    // 8 distinct addrs/wave (k), 96B stride -> 2-way banks: free
                    const float4 w0 = *(const float4*)&s_w[dm * CCH + k * 24 + h3 * 8];
                    const float4 w1 = *(const float4*)&s_w[dm * CCH + k * 24 + h3 * 8 + 4];
                    accA[dm] += dot8(xa0, w0, xa1, w1);
                    accB[dm] += dot8(xv0, w0, xv1, w1);
                }
            }
            float oA = 0.f, oB = 0.f;
            #pragma unroll
            for (int dm = 0; dm < 8; ++dm) {
                float a = accA[dm];
                a += __shfl_xor(a, 1); a += __shfl_xor(a, 2); a += __shfl_xor(a, 4);
                float c = accB[dm];
                c += __shfl_xor(c, 1); c += __shfl_xor(c, 2); c += __shfl_xor(c, 4);
                oA = (dm == k) ? a : oA;
                oB = (dm == k) ? c : oB;
            }
            if (vA) s_d[iA * 8 + k] = qgelu(oA + bd);
            if (vB) s_d[iB * 8 + k] = qgelu(oB + bd);
        }
    }
    __syncthreads();

    // ========== Phase B: conv3x3 + qgelu -> s_d2 (b128 reads) ==========
    for (int j = tid; j < out_count * 8; j += 256) {
        const int nr = j >> 3, o = j & 7;
        const int n = out_start + nr;
        if (n == 1) {
            s_d2[j] = 0.0f;            // dist token zeroed; qgelu(0)=0
        } else if (n == 0) {           // cls: center tap only (half 0: s_d idx0 = tok 0)
            const float4 d0 = *(const float4*)&s_d[0];
            const float4 d1 = *(const float4*)&s_d[4];
            const float4 w0 = *(const float4*)&s_cw[4 * 64 + o * 8];
            const float4 w1 = *(const float4*)&s_cw[4 * 64 + o * 8 + 4];
            s_d2[j] = qgelu(conv_b[o] + dot8(d0, w0, d1, w1));
        } else {
            const int pos = n - 2, h = pos / 14, w = pos % 14;
            float acc = conv_b[o];
            #pragma unroll 1
            for (int dh = -1; dh <= 1; ++dh) {    // unroll 1: cap hoisted-load regs
                const int hh = h + dh;
                if (hh < 0 || hh > 13) continue;
                #pragma unroll
                for (int dw = -1; dw <= 1; ++dw) {
                    const int ww = w + dw;
                    if (ww < 0 || ww > 13) continue;
                    const int tok = 2 + hh * 14 + ww;
                    const int kk  = (dh + 1) * 3 + (dw + 1);
                    const int ti  = tok - d_start;
                    const float4 d0 = *(const float4*)&s_d[ti * 8];
                    const float4 d1 = *(const float4*)&s_d[ti * 8 + 4];
                    const float4 w0 = *(const float4*)&s_cw[kk * 64 + o * 8];
                    const float4 w1 = *(const float4*)&s_cw[kk * 64 + o * 8 + 4];
                    acc += dot8(d0, w0, d1, w1);
                }
            }
            s_d2[j] = qgelu(acc);
        }
    }
    __syncthreads();

    // ========== Phase C: out = d2 @ w_up^T + b_up  (2 channels/thread) ==========
    const int c2 = tid % 96;   // channel pair: channels 2*c2, 2*c2+1
    const int tl = tid / 96;   // 0,1 active; tl==2 (64 threads) idle
    if (tl < 2) {
        const int ch = c2 * 2;
        const float4 wa0 = *(const float4*)(w_up + ch * 8);
        const float4 wa1 = *(const float4*)(w_up + ch * 8 + 4);
        const float4 wb0 = *(const float4*)(w_up + ch * 8 + 8);
        const float4 wb1 = *(const float4*)(w_up + ch * 8 + 12);
        const float bu0 = b_up[ch], bu1 = b_up[ch + 1];
        float* outb = out + ((size_t)b * NTOK + out_start) * CCH;
        #pragma unroll 1
        for (int nr = tl; nr < out_count; nr += 2) {
            const float4 da = *(const float4*)&s_d2[nr * 8];      // broadcast
            const float4 dv = *(const float4*)&s_d2[nr * 8 + 4];
            const vf2 r = {bu0 + dot8(da, wa0, dv, wa1),
                           bu1 + dot8(da, wb0, dv, wb1)};
            __builtin_nontemporal_store(r, (vf2*)(outb + (size_t)nr * CCH + ch));
        }
    }
}

extern "C" void kernel_launch(void* const* d_in, const int* in_sizes, int n_in,
                              void* d_out, int out_size, void* d_ws, size_t ws_size,
                              hipStream_t stream) {
    const float* x      = (const float*)d_in[0];
    const float* w_down = (const float*)d_in[1];
    const float* b_down = (const float*)d_in[2];
    const float* conv_w = (const float*)d_in[3];
    const float* conv_b = (const float*)d_in[4];
    const float* w_up   = (const float*)d_in[5];
    const float* b_up   = (const float*)d_in[6];
    float* out = (float*)d_out;

    const int B = in_sizes[0] / (NTOK * CCH);   // 1024
    convpass_fused<<<dim3(2, B), dim3(256), 0, stream>>>(
        x, w_down, b_down, conv_w, conv_b, w_up, b_up, out);
}

// Round 15
// 86.686 us; speedup vs baseline: 2.5476x; 2.1311x over previous
//
#include <hip/hip_runtime.h>
#include <math.h>

#define NTOK 198
#define CCH  192

typedef float vf4 __attribute__((ext_vector_type(4)));

__device__ __forceinline__ float qgelu(float v) {
    return v / (1.0f + __expf(-1.702f * v));  // x * sigmoid(1.702 x)
}

__device__ __forceinline__ float dot8(const float4& a, const float4& wa,
                                      const float4& b, const float4& wb) {
    return a.x*wa.x + a.y*wa.y + a.z*wa.z + a.w*wa.w
         + b.x*wb.x + b.y*wb.y + b.z*wb.z + b.w*wb.w;
}

// Fully fused: down-proj + qgelu -> conv3x3 + qgelu -> up-proj.
// TWO blocks per batch element (row-split, halo recomputed), 256 thr, grid 2048.
// Register ledger (R7..R14): body needs 86-128 VGPR; cap<=85 (arg2>=3) => scratch
// spill => +300..600MB HBM. (256,2) -> 128 cap, 4 waves/SIMD -- occupancy axis closed.
// R15 = R12 base + Phase C 2-token unroll (batched LDS reads, 2 stores in flight)
// + s_cb staging (kills 800 per-output global scalar loads in Phase B).
__global__ __launch_bounds__(256, 2) void convpass_fused(
    const float* __restrict__ x,       // [B,198,192]
    const float* __restrict__ w_down,  // [8,192]
    const float* __restrict__ b_down,  // [8]
    const float* __restrict__ conv_w,  // [8,8,3,3]
    const float* __restrict__ conv_b,  // [8]
    const float* __restrict__ w_up,    // [192,8]
    const float* __restrict__ b_up,    // [192]
    float* __restrict__ out)           // [B,198,192]
{
    const int half = blockIdx.x;       // 0: cls+dist+rows 0..6 ; 1: rows 7..13
    const int b    = blockIdx.y;
    const int tid  = threadIdx.x;

    // half 0: outputs n in [0,100), needs d tokens [0,114)
    // half 1: outputs n in [100,198), needs d tokens [86,198)
    const int d_start   = half ? 86  : 0;
    const int d_count   = half ? 112 : 114;
    const int out_start = half ? 100 : 0;
    const int out_count = half ? 98  : 100;

    __shared__ float s_w[8 * CCH];    // 6144 B  w_down
    __shared__ float s_d[114 * 8];    // 3648 B  down-proj out (stride 8: b128 rows)
    __shared__ float s_d2[100 * 8];   // 3200 B  conv out
    __shared__ float s_cw[576];       // 2304 B  conv weights [kk][o][i]
    __shared__ float s_cb[8];

    // ---- stage weights ----
    for (int t = tid; t < 8 * CCH; t += 256) s_w[t] = w_down[t];
    for (int t = tid; t < 576; t += 256) {
        const int kk = t >> 6, rem = t & 63, o = rem >> 3, i = rem & 7;
        s_cw[t] = conv_w[(o * 8 + i) * 9 + kk];   // [kk][o][i] <- [o][i][kk]
    }
    if (tid < 8) s_cb[tid] = conv_b[tid];
    __syncthreads();

    // ========== Phase A: d = qgelu(x @ w_down^T + b_down) -> s_d ==========
    // wave = 8 token-slots x 8 c-chunk lanes, TWO rows per lane (w-fragment reuse),
    // 8-float sub-steps (16 live buffer regs).
    {
        const int lane  = tid & 63;
        const int wv    = tid >> 6;       // wave 0..3
        const int t_sub = lane >> 3;      // token-slot 0..7
        const int k     = lane & 7;       // c-chunk (24 floats)
        const float bd  = b_down[k];
        const float* xb = x + (size_t)b * NTOK * CCH;

        #pragma unroll 1
        for (int p = 0; p < 2; ++p) {
            const int iA = p * 64 + wv * 16 + t_sub;
            const int iB = iA + 8;
            const bool vA = (iA < d_count), vB = (iB < d_count);
            const int nA = d_start + (vA ? iA : 0);   // safe addr for masked lanes
            const int nB = d_start + (vB ? iB : 0);
            const float* pA = xb + (size_t)nA * CCH + k * 24;
            const float* pB = xb + (size_t)nB * CCH + k * 24;

            float accA[8] = {0,0,0,0,0,0,0,0};
            float accB[8] = {0,0,0,0,0,0,0,0};
            #pragma unroll
            for (int h3 = 0; h3 < 3; ++h3) {          // 8-float sub-steps
                const float4 xa0 = *(const float4*)(pA + h3 * 8);
                const float4 xa1 = *(const float4*)(pA + h3 * 8 + 4);
                const float4 xv0 = *(const float4*)(pB + h3 * 8);
                const float4 xv1 = *(const float4*)(pB + h3 * 8 + 4);
                #pragma unroll
                for (int dm = 0; dm < 8; ++dm) {
                    // 8 distinct addrs/wave (k), 96B stride -> 2-way banks: free
                    const float4 w0 = *(const float4*)&s_w[dm * CCH + k * 24 + h3 * 8];
                    const float4 w1 = *(const float4*)&s_w[dm * CCH + k * 24 + h3 * 8 + 4];
                    accA[dm] += dot8(xa0, w0, xa1, w1);
                    accB[dm] += dot8(xv0, w0, xv1, w1);
                }
            }
            float oA = 0.f, oB = 0.f;
            #pragma unroll
            for (int dm = 0; dm < 8; ++dm) {
                float a = accA[dm];
                a += __shfl_xor(a, 1); a += __shfl_xor(a, 2); a += __shfl_xor(a, 4);
                float c = accB[dm];
                c += __shfl_xor(c, 1); c += __shfl_xor(c, 2); c += __shfl_xor(c, 4);
                oA = (dm == k) ? a : oA;
                oB = (dm == k) ? c : oB;
            }
            if (vA) s_d[iA * 8 + k] = qgelu(oA + bd);
            if (vB) s_d[iB * 8 + k] = qgelu(oB + bd);
        }
    }
    __syncthreads();

    // ========== Phase B: conv3x3 + qgelu -> s_d2 (b128 reads) ==========
    for (int j = tid; j < out_count * 8; j += 256) {
        const int nr = j >> 3, o = j & 7;
        const int n = out_start + nr;
        if (n == 1) {
            s_d2[j] = 0.0f;            // dist token zeroed; qgelu(0)=0
        } else if (n == 0) {           // cls: center tap only (half 0: s_d idx0 = tok 0)
            const float4 d0 = *(const float4*)&s_d[0];
            const float4 d1 = *(const float4*)&s_d[4];
            const float4 w0 = *(const float4*)&s_cw[4 * 64 + o * 8];
            const float4 w1 = *(const float4*)&s_cw[4 * 64 + o * 8 + 4];
            s_d2[j] = qgelu(s_cb[o] + dot8(d0, w0, d1, w1));
        } else {
            const int pos = n - 2, h = pos / 14, w = pos % 14;
            float acc = s_cb[o];
            #pragma unroll
            for (int dh = -1; dh <= 1; ++dh) {
                const int hh = h + dh;
                if (hh < 0 || hh > 13) continue;
                #pragma unroll
                for (int dw = -1; dw <= 1; ++dw) {
                    const int ww = w + dw;
                    if (ww < 0 || ww > 13) continue;
                    const int tok = 2 + hh * 14 + ww;
                    const int kk  = (dh + 1) * 3 + (dw + 1);
                    const int ti  = tok - d_start;
                    const float4 d0 = *(const float4*)&s_d[ti * 8];
                    const float4 d1 = *(const float4*)&s_d[ti * 8 + 4];
                    const float4 w0 = *(const float4*)&s_cw[kk * 64 + o * 8];
                    const float4 w1 = *(const float4*)&s_cw[kk * 64 + o * 8 + 4];
                    acc += dot8(d0, w0, d1, w1);
                }
            }
            s_d2[j] = qgelu(acc);
        }
    }
    __syncthreads();

    // ========== Phase C: out = d2 @ w_up^T + b_up  (4 ch/thread, 2-token unroll) ==========
    const int c4 = tid % 48;
    const int tl = tid / 48;  // 0..5 (tl==5: 16 threads idle)
    if (tl < 5) {
        float w_r[4][8];
        #pragma unroll
        for (int cc = 0; cc < 4; ++cc) {
            const float4 wa = *(const float4*)(w_up + (c4 * 4 + cc) * 8);
            const float4 wb = *(const float4*)(w_up + (c4 * 4 + cc) * 8 + 4);
            w_r[cc][0] = wa.x; w_r[cc][1] = wa.y; w_r[cc][2] = wa.z; w_r[cc][3] = wa.w;
            w_r[cc][4] = wb.x; w_r[cc][5] = wb.y; w_r[cc][6] = wb.z; w_r[cc][7] = wb.w;
        }
        const float4 bu = *(const float4*)(b_up + c4 * 4);
        float* outb = out + ((size_t)b * NTOK + out_start) * CCH;
        #pragma unroll 1
        for (int nr = tl; nr < out_count; nr += 10) {
            const int nrB = nr + 5;
            const bool vB = (nrB < out_count);
            const int nrBs = vB ? nrB : nr;     // safe LDS addr for masked tail
            // batch the 4 b128 LDS reads -> two independent FMA chains
            const float4 da0 = *(const float4*)&s_d2[nr * 8];
            const float4 dv0 = *(const float4*)&s_d2[nr * 8 + 4];
            const float4 da1 = *(const float4*)&s_d2[nrBs * 8];
            const float4 dv1 = *(const float4*)&s_d2[nrBs * 8 + 4];
            float a0[4] = {bu.x, bu.y, bu.z, bu.w};
            float a1[4] = {bu.x, bu.y, bu.z, bu.w};
            #pragma unroll
            for (int cc = 0; cc < 4; ++cc) {
                a0[cc] += da0.x * w_r[cc][0] + da0.y * w_r[cc][1]
                        + da0.z * w_r[cc][2] + da0.w * w_r[cc][3]
                        + dv0.x * w_r[cc][4] + dv0.y * w_r[cc][5]
                        + dv0.z * w_r[cc][6] + dv0.w * w_r[cc][7];
                a1[cc] += da1.x * w_r[cc][0] + da1.y * w_r[cc][1]
                        + da1.z * w_r[cc][2] + da1.w * w_r[cc][3]
                        + dv1.x * w_r[cc][4] + dv1.y * w_r[cc][5]
                        + dv1.z * w_r[cc][6] + dv1.w * w_r[cc][7];
            }
            const vf4 r0 = {a0[0], a0[1], a0[2], a0[3]};
            __builtin_nontemporal_store(r0, (vf4*)(outb + (size_t)nr * CCH + c4 * 4));
            if (vB) {
                const vf4 r1 = {a1[0], a1[1], a1[2], a1[3]};
                __builtin_nontemporal_store(r1, (vf4*)(outb + (size_t)nrB * CCH + c4 * 4));
            }
        }
    }
}

extern "C" void kernel_launch(void* const* d_in, const int* in_sizes, int n_in,
                              void* d_out, int out_size, void* d_ws, size_t ws_size,
                              hipStream_t stream) {
    const float* x      = (const float*)d_in[0];
    const float* w_down = (const float*)d_in[1];
    const float* b_down = (const float*)d_in[2];
    const float* conv_w = (const float*)d_in[3];
    const float* conv_b = (const float*)d_in[4];
    const float* w_up   = (const float*)d_in[5];
    const float* b_up   = (const float*)d_in[6];
    float* out = (float*)d_out;

    const int B = in_sizes[0] / (NTOK * CCH);   // 1024
    convpass_fused<<<dim3(2, B), dim3(256), 0, stream>>>(
        x, w_down, b_down, conv_w, conv_b, w_up, b_up, out);
}

// Round 16
// 77.667 us; speedup vs baseline: 2.8435x; 1.1161x over previous
//
#include <hip/hip_runtime.h>
#include <math.h>

#define NTOK 198
#define CCH  192

typedef float vf4 __attribute__((ext_vector_type(4)));

__device__ __forceinline__ float qgelu(float v) {
    return v / (1.0f + __expf(-1.702f * v));  // x * sigmoid(1.702 x)
}

__device__ __forceinline__ float dot8(const float4& a, const float4& wa,
                                      const float4& b, const float4& wb) {
    return a.x*wa.x + a.y*wa.y + a.z*wa.z + a.w*wa.w
         + b.x*wb.x + b.y*wb.y + b.z*wb.z + b.w*wb.w;
}

// Fully fused: down-proj + qgelu -> conv3x3 + qgelu -> up-proj.
// TWO blocks per batch element (row-split, halo recomputed), 256 thr, grid 2048.
// R16: Phase A redesigned for a <=64-VGPR body -> 8 waves/SIMD (2x R12 occupancy).
//   lane=(chunk,dim): w_down[dim][chunk*24..+24) lives in 24 REGISTERS (no LDS
//   staging, no w LDS reads); per token: 24-FMA partial dot + 3 shfl_xor(8/16/32)
//   + 8-lane d write. Phase B/C = R12's proven versions (~35-50 live regs).
// Ledger: R13's 64-cap spill was the OLD 124-reg body; this one is designed to fit.
// Spill tell = FETCH >> 90MB.
__global__ __launch_bounds__(256, 4) void convpass_fused(
    const float* __restrict__ x,       // [B,198,192]
    const float* __restrict__ w_down,  // [8,192]
    const float* __restrict__ b_down,  // [8]
    const float* __restrict__ conv_w,  // [8,8,3,3]
    const float* __restrict__ conv_b,  // [8]
    const float* __restrict__ w_up,    // [192,8]
    const float* __restrict__ b_up,    // [192]
    float* __restrict__ out)           // [B,198,192]
{
    const int half = blockIdx.x;       // 0: cls+dist+rows 0..6 ; 1: rows 7..13
    const int b    = blockIdx.y;
    const int tid  = threadIdx.x;

    // half 0: outputs n in [0,100), needs d tokens [0,114)
    // half 1: outputs n in [100,198), needs d tokens [86,198)
    const int d_start   = half ? 86  : 0;
    const int d_count   = half ? 112 : 114;
    const int out_start = half ? 100 : 0;
    const int out_count = half ? 98  : 100;

    __shared__ float s_d[114 * 8];    // 3648 B  down-proj out (stride 8: b128 rows)
    __shared__ float s_d2[100 * 8];   // 3200 B  conv out
    __shared__ float s_cw[576];       // 2304 B  conv weights [kk][o][i]
    __shared__ float s_cb[8];

    // ---- stage conv weights (visibility covered by the barrier after Phase A) ----
    for (int t = tid; t < 576; t += 256) {
        const int kk = t >> 6, rem = t & 63, o = rem >> 3, i = rem & 7;
        s_cw[t] = conv_w[(o * 8 + i) * 9 + kk];   // [kk][o][i] <- [o][i][kk]
    }
    if (tid < 8) s_cb[tid] = conv_b[tid];

    // ========== Phase A: d = qgelu(x @ w_down^T + b_down) -> s_d ==========
    // lane = chunk*8 + dim; w fragment in regs; 1 token per wave-iteration.
    {
        const int lane  = tid & 63;
        const int wv    = tid >> 6;       // wave 0..3
        const int chunk = lane >> 3;      // 24-float c-chunk 0..7
        const int dim   = lane & 7;       // output dim 0..7

        float wreg[24];
        {
            const float* wp = w_down + dim * CCH + chunk * 24;
            #pragma unroll
            for (int j = 0; j < 24; ++j) wreg[j] = wp[j];
        }
        const float bd  = b_down[dim];
        const float* xb = x + (size_t)b * NTOK * CCH + chunk * 24;

        #pragma unroll 1
        for (int i = 0; i < 29; ++i) {
            const int idx = i * 4 + wv;               // 0..115
            const bool valid = (idx < d_count);
            const int n = d_start + (valid ? idx : 0);  // safe addr for masked lanes
            const float* xr = xb + (size_t)n * CCH;
            // 6 independent b128 loads (8-lane broadcast groups), 2 FMA chains
            float a0 = 0.f, a1 = 0.f;
            #pragma unroll
            for (int j = 0; j < 3; ++j) {
                const float4 xv = *(const float4*)(xr + j * 8);
                const float4 xw = *(const float4*)(xr + j * 8 + 4);
                a0 += xv.x*wreg[j*8]   + xv.y*wreg[j*8+1] + xv.z*wreg[j*8+2] + xv.w*wreg[j*8+3];
                a1 += xw.x*wreg[j*8+4] + xw.y*wreg[j*8+5] + xw.z*wreg[j*8+6] + xw.w*wreg[j*8+7];
            }
            float acc = a0 + a1;
            // all-reduce over the 8 chunks (lane bits 3,4,5)
            acc += __shfl_xor(acc, 8);
            acc += __shfl_xor(acc, 16);
            acc += __shfl_xor(acc, 32);
            if (valid && lane < 8) s_d[idx * 8 + dim] = qgelu(acc + bd);
        }
    }
    __syncthreads();

    // ========== Phase B: conv3x3 + qgelu -> s_d2 (b128 reads, conflict-free) ==========
    for (int j = tid; j < out_count * 8; j += 256) {
        const int nr = j >> 3, o = j & 7;
        const int n = out_start + nr;
        if (n == 1) {
            s_d2[j] = 0.0f;            // dist token zeroed; qgelu(0)=0
        } else if (n == 0) {           // cls: center tap only (half 0: s_d idx0 = tok 0)
            const float4 d0 = *(const float4*)&s_d[0];
            const float4 d1 = *(const float4*)&s_d[4];
            const float4 w0 = *(const float4*)&s_cw[4 * 64 + o * 8];
            const float4 w1 = *(const float4*)&s_cw[4 * 64 + o * 8 + 4];
            s_d2[j] = qgelu(s_cb[o] + dot8(d0, w0, d1, w1));
        } else {
            const int pos = n - 2, h = pos / 14, w = pos % 14;
            float acc = s_cb[o];
            #pragma unroll
            for (int dh = -1; dh <= 1; ++dh) {
                const int hh = h + dh;
                if (hh < 0 || hh > 13) continue;
                #pragma unroll
                for (int dw = -1; dw <= 1; ++dw) {
                    const int ww = w + dw;
                    if (ww < 0 || ww > 13) continue;
                    const int tok = 2 + hh * 14 + ww;
                    const int kk  = (dh + 1) * 3 + (dw + 1);
                    const int ti  = tok - d_start;
                    const float4 d0 = *(const float4*)&s_d[ti * 8];
                    const float4 d1 = *(const float4*)&s_d[ti * 8 + 4];
                    const float4 w0 = *(const float4*)&s_cw[kk * 64 + o * 8];
                    const float4 w1 = *(const float4*)&s_cw[kk * 64 + o * 8 + 4];
                    acc += dot8(d0, w0, d1, w1);
                }
            }
            s_d2[j] = qgelu(acc);
        }
    }
    __syncthreads();

    // ========== Phase C: out = d2 @ w_up^T + b_up  (R12's proven version) ==========
    const int c4 = tid % 48;
    const int tl = tid / 48;  // 0..5 (tl==5: 16 threads idle)
    if (tl < 5) {
        float w_r[4][8];
        #pragma unroll
        for (int cc = 0; cc < 4; ++cc) {
            const float4 wa = *(const float4*)(w_up + (c4 * 4 + cc) * 8);
            const float4 wb = *(const float4*)(w_up + (c4 * 4 + cc) * 8 + 4);
            w_r[cc][0] = wa.x; w_r[cc][1] = wa.y; w_r[cc][2] = wa.z; w_r[cc][3] = wa.w;
            w_r[cc][4] = wb.x; w_r[cc][5] = wb.y; w_r[cc][6] = wb.z; w_r[cc][7] = wb.w;
        }
        const float4 bu = *(const float4*)(b_up + c4 * 4);
        float* outb = out + ((size_t)b * NTOK + out_start) * CCH;
        #pragma unroll 1
        for (int nr = tl; nr < out_count; nr += 5) {
            const float4 da = *(const float4*)&s_d2[nr * 8];      // broadcast
            const float4 dv = *(const float4*)&s_d2[nr * 8 + 4];
            float accs[4] = {bu.x, bu.y, bu.z, bu.w};
            #pragma unroll
            for (int cc = 0; cc < 4; ++cc) {
                accs[cc] += da.x * w_r[cc][0] + da.y * w_r[cc][1]
                          + da.z * w_r[cc][2] + da.w * w_r[cc][3]
                          + dv.x * w_r[cc][4] + dv.y * w_r[cc][5]
                          + dv.z * w_r[cc][6] + dv.w * w_r[cc][7];
            }
            const vf4 r = {accs[0], accs[1], accs[2], accs[3]};
            __builtin_nontemporal_store(r, (vf4*)(outb + (size_t)nr * CCH + c4 * 4));
        }
    }
}

extern "C" void kernel_launch(void* const* d_in, const int* in_sizes, int n_in,
                              void* d_out, int out_size, void* d_ws, size_t ws_size,
                              hipStream_t stream) {
    const float* x      = (const float*)d_in[0];
    const float* w_down = (const float*)d_in[1];
    const float* b_down = (const float*)d_in[2];
    const float* conv_w = (const float*)d_in[3];
    const float* conv_b = (const float*)d_in[4];
    const float* w_up   = (const float*)d_in[5];
    const float* b_up   = (const float*)d_in[6];
    float* out = (float*)d_out;

    const int B = in_sizes[0] / (NTOK * CCH);   // 1024
    convpass_fused<<<dim3(2, B), dim3(256), 0, stream>>>(
        x, w_down, b_down, conv_w, conv_b, w_up, b_up, out);
}